// Round 8
// baseline (309.245 us; speedup 1.0000x reference)
//
#include <hip/hip_runtime.h>
#include <hip/hip_bf16.h>

typedef __attribute__((ext_vector_type(8))) short bf16x8;
typedef __attribute__((ext_vector_type(4))) short bf16x4;
typedef __attribute__((ext_vector_type(4))) float f32x4;

#define NR  4   // rounds per block
#define WPB 8   // waves per block (one batch per wave per round)

#define A3  0.33333334f
#define B4  0.25f
#define C34 0.28867513f

// Per-row sparse A_hat (includes diagonal): up to 4 (neighbor, weight) pairs.
__device__ const int ADJ_IDX[16][4] = {
  {0,1,7,0},{1,0,2,8},{2,1,3,9},{3,2,4,10},
  {4,3,5,11},{5,4,6,12},{6,5,13,0},{7,0,8,0},
  {8,7,9,1},{9,8,10,2},{10,9,11,3},{11,10,12,4},
  {12,11,13,5},{13,12,6,0},{0,0,0,0},{0,0,0,0}
};
__device__ const float ADJ_W[16][4] = {
  {A3,C34,A3,0.f},{B4,C34,B4,B4},{B4,B4,B4,B4},{B4,B4,B4,B4},
  {B4,B4,B4,B4},{B4,B4,C34,B4},{A3,C34,A3,0.f},{A3,A3,C34,0.f},
  {B4,C34,B4,B4},{B4,B4,B4,B4},{B4,B4,B4,B4},{B4,B4,B4,B4},
  {B4,B4,C34,B4},{A3,C34,A3,0.f},{0.f,0.f,0.f,0.f},{0.f,0.f,0.f,0.f}
};

__device__ __forceinline__ unsigned short f2b(float x) {
  unsigned u = __builtin_bit_cast(unsigned, x);
  u += 0x7FFFu + ((u >> 16) & 1u);   // RNE bf16
  return (unsigned short)(u >> 16);
}
// packed f32x2 -> bf16x2 (emits v_cvt_pk_bf16_f32)
__device__ __forceinline__ unsigned pk2(float lo, float hi) {
  float2 t; t.x = lo; t.y = hi;
  __hip_bfloat162 h = __float22bfloat162_rn(t);
  unsigned u; __builtin_memcpy(&u, &h, 4);
  return u;
}
__device__ __forceinline__ bf16x4 mk4(unsigned lo, unsigned hi) {
  uint2 u; u.x = lo; u.y = hi;
  return __builtin_bit_cast(bf16x4, u);
}

#if __has_builtin(__builtin_amdgcn_mfma_f32_16x16x16_bf16)
#define MFMA16(a, b, c) __builtin_amdgcn_mfma_f32_16x16x16_bf16((a), (b), (c), 0, 0, 0)
#elif __has_builtin(__builtin_amdgcn_mfma_f32_16x16x16bf16_1k)
#define MFMA16(a, b, c) __builtin_amdgcn_mfma_f32_16x16x16bf16_1k((a), (b), (c), 0, 0, 0)
#else
__device__ __forceinline__ f32x4 mfma16_asm(bf16x4 a, bf16x4 b, f32x4 c) {
  f32x4 d;
  asm("v_mfma_f32_16x16x16_bf16 %0, %1, %2, %3\n\ts_nop 7\n\ts_nop 7"
      : "=v"(d) : "v"(a), "v"(b), "v"(c));
  return d;
}
#define MFMA16(a, b, c) mfma16_asm((a), (b), (c))
#endif

// Raw barrier: orders LDS (lgkmcnt(0)) but does NOT drain vmcnt ->
// global prefetch loads stay in flight across it.
#define BAR() do {                                        \
  __builtin_amdgcn_sched_barrier(0);                      \
  asm volatile("s_waitcnt lgkmcnt(0)" ::: "memory");      \
  __builtin_amdgcn_s_barrier();                           \
  __builtin_amdgcn_sched_barrier(0);                      \
} while (0)

// ---------- weight prep (fragments live in d_ws, read from global/L2) -----
// W1 (K=32 B-frags): frag (nt*8+kk); lane holds W1[kk*32+lgrp*8+j][nt*16+lrow],
//   j=0..8 (16B).  At wf ushort-offset [0, 32768).
// W2 (K=16 B-frags, PAIRED): uint4 index (nt*4+kp)*64+lane holds frags
//   kt2=2kp (xy) and kt2=2kp+1 (zw): W2[kt2*16+lgrp*4+i][nt*16+lrow], i=0..4.
//   At wf ushort-offset [32768, 40960).
__global__ __launch_bounds__(256) void prep_w(
    const float* __restrict__ W1, const float* __restrict__ W2,
    unsigned short* __restrict__ wf)
{
  const int f = blockIdx.x * 256 + threadIdx.x;   // 20 blocks -> 5120
  if (f < 4096) {
    const int lane = f & 63, kk = (f >> 6) & 7, nt = f >> 9;
    const int col = nt * 16 + (lane & 15);
    const int k0  = kk * 32 + (lane >> 4) * 8;
    unsigned short tmp[8];
    #pragma unroll
    for (int j = 0; j < 8; ++j) tmp[j] = f2b(W1[(k0 + j) * 128 + col]);
    *(uint4*)(wf + (size_t)f * 8) = *(const uint4*)tmp;
  } else if (f < 5120) {
    const int f2i = f - 4096;                     // 0..1023
    const int lane = f2i & 63, kp = (f2i >> 6) & 3, nt = f2i >> 8;
    const int col = nt * 16 + (lane & 15);
    const int k0  = kp * 32 + (lane >> 4) * 4;    // kt2=2kp -> k = 2kp*16 + lgrp*4
    uint4 q;
    q.x = (unsigned)f2b(W2[(k0 + 0) * 64 + col]) | ((unsigned)f2b(W2[(k0 + 1) * 64 + col]) << 16);
    q.y = (unsigned)f2b(W2[(k0 + 2) * 64 + col]) | ((unsigned)f2b(W2[(k0 + 3) * 64 + col]) << 16);
    q.z = (unsigned)f2b(W2[(k0 + 16) * 64 + col]) | ((unsigned)f2b(W2[(k0 + 17) * 64 + col]) << 16);
    q.w = (unsigned)f2b(W2[(k0 + 18) * 64 + col]) | ((unsigned)f2b(W2[(k0 + 19) * 64 + col]) << 16);
    *(uint4*)(wf + 32768 + (size_t)f2i * 8) = q;
  }
}

__global__ __launch_bounds__(512) void fpm_kernel(
    const float* __restrict__ X,
    const unsigned short* __restrict__ wf,
    const float* __restrict__ b1, const float* __restrict__ b2,
    float* __restrict__ out, int Btot)
{
  // 8 batch tiles of [16 rows][256 bf16] = 8 KiB each, XOR-swizzled rows.
  __shared__ __align__(16) char XS[WPB * 8192];   // 64 KiB

  const int tid  = threadIdx.x;
  const int lane = tid & 63;
  const int wv   = tid >> 6;      // 0..7
  const int lrow = lane & 15;
  const int lgrp = lane >> 4;

  const bf16x8* W1v = (const bf16x8*)wf;           // K32 B-frags
  const uint4*  W2p = (const uint4*)(wf + 32768);  // paired K16 B-frags

  // ---- A_hat K16 B-fragment: B[k=4*lgrp+i][n=lrow]; k=14 row = 1 (bias) ----
  unsigned amx0, amx1;
  {
    float v[4];
    #pragma unroll
    for (int i = 0; i < 4; ++i) {
      const int k = lgrp * 4 + i;
      float s = 0.f;
      if (k == 14) s = 1.f;
      else if (k < 14 && lrow < 14) {
        #pragma unroll
        for (int t = 0; t < 4; ++t)
          if (ADJ_IDX[k][t] == lrow) s += ADJ_W[k][t];
      }
      v[i] = s;
    }
    amx0 = pk2(v[0], v[1]);
    amx1 = pk2(v[2], v[3]);
  }
  const bf16x4 amx = mk4(amx0, amx1);

  unsigned b1inj[8], b2inj[4];
  #pragma unroll
  for (int mt = 0; mt < 8; ++mt) b1inj[mt] = (unsigned)f2b(b1[mt * 16 + lrow]);
  #pragma unroll
  for (int nt = 0; nt < 4; ++nt) b2inj[nt] = (unsigned)f2b(b2[nt * 16 + lrow]);
  const bool isg3 = (lgrp == 3);

  const int base  = blockIdx.x * (WPB * NR);
  const int f4max = Btot * 896 - 1;   // last valid float4 index in X

  float4 raw[14];   // coalesced staging regs (one 8-batch set / 512 threads)
  uint2  cvt[14];   // bf16-packed version

  // ---- coalesced load of batch-set s (contiguous 28 KB per block) ----
  auto issueLoads = [&](int s) {
    const int gbase = (base + s * WPB) * 896;
    #pragma unroll
    for (int i = 0; i < 14; ++i) {
      int fi = gbase + i * 512 + tid;
      if (fi > f4max) fi = f4max;            // clamp (real data, no NaN)
      raw[i] = *(const float4*)(X + (size_t)fi * 4);
    }
  };
  auto cvtRaw = [&] {
    #pragma unroll
    for (int i = 0; i < 14; ++i) {
      cvt[i].x = pk2(raw[i].x, raw[i].y);
      cvt[i].y = pk2(raw[i].z, raw[i].w);
    }
  };
  auto writeStage = [&] {
    #pragma unroll
    for (int i = 0; i < 14; ++i) {
      const int g = i * 512 + tid;           // float4 idx within 8-batch set
      const int bset = g / 896;
      const int rem  = g - bset * 896;
      const int row  = rem >> 6, col4 = rem & 63;
      *(uint2*)(XS + bset * 8192 +
                (((row * 512 + col4 * 8)) ^ ((row & 7) << 4))) = cvt[i];
    }
  };

  // ---- prologue ----
  issueLoads(0);
  {  // zero rows 14,15 of every tile (never rewritten; kills NaN paths)
    const int bset = tid >> 6, row = 14 + ((tid >> 5) & 1), c16 = tid & 31;
    uint4 z = {0, 0, 0, 0};
    *(uint4*)(XS + bset * 8192 + (((row * 512 + c16 * 16)) ^ ((row & 7) << 4))) = z;
  }
  cvtRaw(); writeStage();
  BAR();                    // stage(set 0) + zero rows visible
  if (NR > 1) issueLoads(1);

  const f32x4 zacc = {0.f, 0.f, 0.f, 0.f};

  for (int r = 0; r < NR; ++r) {
    const int b = base + r * WPB + wv;       // this wave's batch (wave-uniform)

    if (r + 1 < NR) cvtRaw();                // convert set r+1; frees raw regs

    // ---------- GEMM1: G = Xb * W1 (M16 x N128 x K256); A from LDS ----------
    const char* myT = XS + wv * 8192;
    f32x4 acc1[8];
    #pragma unroll
    for (int nt = 0; nt < 8; ++nt) acc1[nt] = zacc;
    __builtin_amdgcn_s_setprio(1);
    #pragma unroll
    for (int kk = 0; kk < 8; ++kk) {
      const bf16x8 a = *(const bf16x8*)(myT +
          ((lrow * 512 + kk * 64 + lgrp * 16) ^ ((lrow & 7) << 4)));
      #pragma unroll
      for (int nt = 0; nt < 8; ++nt)
        acc1[nt] = __builtin_amdgcn_mfma_f32_16x16x32_bf16(
            a, W1v[(nt * 8 + kk) * 64 + lane], acc1[nt], 0, 0, 0);
    }
    __builtin_amdgcn_s_setprio(0);

    BAR();                                   // A: all waves done reading stage
    if (r + 1 < NR) writeStage();            // stage set r+1
    BAR();                                   // B: stage(r+1) visible
    if (r + 2 < NR) issueLoads(r + 2);       // in flight across next round

    // ---------- mix1: H1^T = G^T * Ahat_ext (K=16, lane-local A-frags) ------
    unsigned h1p[8][2];
    #pragma unroll
    for (int mt = 0; mt < 8; ++mt) {
      const unsigned a0 = pk2(acc1[mt][0], acc1[mt][1]);
      const unsigned a1 = isg3 ? b1inj[mt] : pk2(acc1[mt][2], acc1[mt][3]);
      const f32x4 h = MFMA16(mk4(a0, a1), amx, zacc);
      h1p[mt][0] = pk2(fmaxf(h[0], 0.f), fmaxf(h[1], 0.f));
      h1p[mt][1] = pk2(fmaxf(h[2], 0.f), fmaxf(h[3], 0.f));
    }

    // ---------- GEMM2: C2 = H1 * W2 (M16 x N64 x K128); B from global -------
    f32x4 acc2[4];
    #pragma unroll
    for (int nt = 0; nt < 4; ++nt) acc2[nt] = zacc;
    __builtin_amdgcn_s_setprio(1);
    #pragma unroll
    for (int kp = 0; kp < 4; ++kp) {
      const bf16x4 aE = mk4(h1p[2 * kp][0],     h1p[2 * kp][1]);
      const bf16x4 aO = mk4(h1p[2 * kp + 1][0], h1p[2 * kp + 1][1]);
      #pragma unroll
      for (int nt = 0; nt < 4; ++nt) {
        const uint4 w = W2p[(nt * 4 + kp) * 64 + lane];
        acc2[nt] = MFMA16(aE, mk4(w.x, w.y), acc2[nt]);
        acc2[nt] = MFMA16(aO, mk4(w.z, w.w), acc2[nt]);
      }
    }
    __builtin_amdgcn_s_setprio(0);

    // ---------- mix2: out^T = C2^T * Ahat_ext (+b2 via k=14); store ---------
    float* outB = out + (size_t)b * 896;
    #pragma unroll
    for (int nt = 0; nt < 4; ++nt) {
      const unsigned a0 = pk2(acc2[nt][0], acc2[nt][1]);
      const unsigned a1 = isg3 ? b2inj[nt] : pk2(acc2[nt][2], acc2[nt][3]);
      const f32x4 o = MFMA16(mk4(a0, a1), amx, zacc);
      if (b < Btot && lrow < 14) {
        float4 st; st.x = o[0]; st.y = o[1]; st.z = o[2]; st.w = o[3];
        *(float4*)(outB + lrow * 64 + nt * 16 + lgrp * 4) = st;
      }
    }
  }
}

extern "C" void kernel_launch(void* const* d_in, const int* in_sizes, int n_in,
                              void* d_out, int out_size, void* d_ws, size_t ws_size,
                              hipStream_t stream) {
  (void)n_in; (void)out_size; (void)ws_size;
  const float* fea = (const float*)d_in[0];
  const float* W1  = (const float*)d_in[1];
  const float* b1  = (const float*)d_in[2];
  const float* W2  = (const float*)d_in[3];
  const float* b2  = (const float*)d_in[4];
  float* out = (float*)d_out;
  const int Btot = in_sizes[0] / (14 * 256);

  unsigned short* wf = (unsigned short*)d_ws;    // needs 80 KiB of d_ws
  prep_w<<<20, 256, 0, stream>>>(W1, W2, wf);

  const int per_block = WPB * NR;
  const int grid = (Btot + per_block - 1) / per_block;
  fpm_kernel<<<grid, 512, 0, stream>>>(fea, wf, b1, b2, out, Btot);
}

// Round 9
// 128.785 us; speedup vs baseline: 2.4013x; 2.4013x over previous
//
#include <hip/hip_runtime.h>
#include <hip/hip_bf16.h>

typedef __attribute__((ext_vector_type(8))) short bf16x8;
typedef __attribute__((ext_vector_type(4))) short bf16x4;
typedef __attribute__((ext_vector_type(4))) float f32x4;

#define NPW 4   // batches per wave

#define A3  0.33333334f
#define B4  0.25f
#define C34 0.28867513f

// Per-row sparse A_hat (includes diagonal): up to 4 (neighbor, weight) pairs.
__device__ const int ADJ_IDX[16][4] = {
  {0,1,7,0},{1,0,2,8},{2,1,3,9},{3,2,4,10},
  {4,3,5,11},{5,4,6,12},{6,5,13,0},{7,0,8,0},
  {8,7,9,1},{9,8,10,2},{10,9,11,3},{11,10,12,4},
  {12,11,13,5},{13,12,6,0},{0,0,0,0},{0,0,0,0}
};
__device__ const float ADJ_W[16][4] = {
  {A3,C34,A3,0.f},{B4,C34,B4,B4},{B4,B4,B4,B4},{B4,B4,B4,B4},
  {B4,B4,B4,B4},{B4,B4,C34,B4},{A3,C34,A3,0.f},{A3,A3,C34,0.f},
  {B4,C34,B4,B4},{B4,B4,B4,B4},{B4,B4,B4,B4},{B4,B4,B4,B4},
  {B4,B4,C34,B4},{A3,C34,A3,0.f},{0.f,0.f,0.f,0.f},{0.f,0.f,0.f,0.f}
};

__device__ __forceinline__ unsigned short f2b(float x) {
  unsigned u = __builtin_bit_cast(unsigned, x);
  u += 0x7FFFu + ((u >> 16) & 1u);   // RNE bf16
  return (unsigned short)(u >> 16);
}
// packed f32x2 -> bf16x2 (emits v_cvt_pk_bf16_f32)
__device__ __forceinline__ unsigned pk2(float lo, float hi) {
  float2 t; t.x = lo; t.y = hi;
  __hip_bfloat162 h = __float22bfloat162_rn(t);
  unsigned u; __builtin_memcpy(&u, &h, 4);
  return u;
}
__device__ __forceinline__ bf16x4 mk4(unsigned lo, unsigned hi) {
  uint2 u; u.x = lo; u.y = hi;
  return __builtin_bit_cast(bf16x4, u);
}

#if __has_builtin(__builtin_amdgcn_mfma_f32_16x16x16_bf16)
#define MFMA16(a, b, c) __builtin_amdgcn_mfma_f32_16x16x16_bf16((a), (b), (c), 0, 0, 0)
#elif __has_builtin(__builtin_amdgcn_mfma_f32_16x16x16bf16_1k)
#define MFMA16(a, b, c) __builtin_amdgcn_mfma_f32_16x16x16bf16_1k((a), (b), (c), 0, 0, 0)
#else
__device__ __forceinline__ f32x4 mfma16_asm(bf16x4 a, bf16x4 b, f32x4 c) {
  f32x4 d;
  asm("v_mfma_f32_16x16x16_bf16 %0, %1, %2, %3\n\ts_nop 7\n\ts_nop 7"
      : "=v"(d) : "v"(a), "v"(b), "v"(c));
  return d;
}
#define MFMA16(a, b, c) mfma16_asm((a), (b), (c))
#endif

// ---------- weight prep ----------
// W1 (K=32 B-frags): frag (nt*8+kk); lane holds W1[kk*32+lgrp*8+j][nt*16+lrow],
//   j=0..8 (16B). At wf ushort-offset [0, 32768).
// W2 (K=16 B-frags, PAIRED): uint4 index (nt*4+kp)*64+lane holds frags
//   kt2=2kp (xy) and kt2=2kp+1 (zw): W2[kt2*16+lgrp*4+i][nt*16+lrow], i=0..4.
//   At wf ushort-offset [32768, 40960).
__global__ __launch_bounds__(256) void prep_w(
    const float* __restrict__ W1, const float* __restrict__ W2,
    unsigned short* __restrict__ wf)
{
  const int f = blockIdx.x * 256 + threadIdx.x;   // 20 blocks -> 5120
  if (f < 4096) {
    const int lane = f & 63, kk = (f >> 6) & 7, nt = f >> 9;
    const int col = nt * 16 + (lane & 15);
    const int k0  = kk * 32 + (lane >> 4) * 8;
    unsigned short tmp[8];
    #pragma unroll
    for (int j = 0; j < 8; ++j) tmp[j] = f2b(W1[(k0 + j) * 128 + col]);
    *(uint4*)(wf + (size_t)f * 8) = *(const uint4*)tmp;
  } else if (f < 5120) {
    const int f2i = f - 4096;                     // 0..1023
    const int lane = f2i & 63, kp = (f2i >> 6) & 3, nt = f2i >> 8;
    const int col = nt * 16 + (lane & 15);
    const int k0  = kp * 32 + (lane >> 4) * 4;    // kt2=2kp -> k = 2kp*16 + lgrp*4
    uint4 q;
    q.x = (unsigned)f2b(W2[(k0 + 0) * 64 + col]) | ((unsigned)f2b(W2[(k0 + 1) * 64 + col]) << 16);
    q.y = (unsigned)f2b(W2[(k0 + 2) * 64 + col]) | ((unsigned)f2b(W2[(k0 + 3) * 64 + col]) << 16);
    q.z = (unsigned)f2b(W2[(k0 + 16) * 64 + col]) | ((unsigned)f2b(W2[(k0 + 17) * 64 + col]) << 16);
    q.w = (unsigned)f2b(W2[(k0 + 18) * 64 + col]) | ((unsigned)f2b(W2[(k0 + 19) * 64 + col]) << 16);
    *(uint4*)(wf + 32768 + (size_t)f2i * 8) = q;
  }
}

__global__ __launch_bounds__(512, 4) void fpm_kernel(
    const float* __restrict__ X,
    const unsigned short* __restrict__ wf,
    const float* __restrict__ b1, const float* __restrict__ b2,
    float* __restrict__ out, int Btot)
{
  __shared__ __align__(16) uint4 WL1[4096];   // 64 KiB W1 frags
  __shared__ __align__(16) uint4 WL2[1024];   // 16 KiB paired W2 frags

  const int tid  = threadIdx.x;
  const int lane = tid & 63;
  const int wv   = tid >> 6;      // 0..7
  const int lrow = lane & 15;
  const int lgrp = lane >> 4;

  const int gw    = blockIdx.x * 8 + wv;
  const int bbase = gw * NPW;

  // ---- issue first batch's X loads ASAP ----
  float4 raw[16];
  #pragma unroll
  for (int i = 0; i < 16; ++i) raw[i] = float4{0.f, 0.f, 0.f, 0.f};
  if (bbase < Btot && lrow < 14) {
    const float* Xp = X + (size_t)bbase * 3584 + lrow * 256 + lgrp * 8;
    #pragma unroll
    for (int kk = 0; kk < 8; ++kk) {
      raw[2 * kk]     = *(const float4*)(Xp + kk * 32);
      raw[2 * kk + 1] = *(const float4*)(Xp + kk * 32 + 4);
    }
  }

  // ---- one-time LDS fill (read-only afterwards) ----
  #pragma unroll
  for (int i = 0; i < 8; ++i)
    WL1[i * 512 + tid] = ((const uint4*)wf)[i * 512 + tid];
  if (tid < 256) {
    const uint4* wf2 = (const uint4*)(wf + 32768);
    #pragma unroll
    for (int i = 0; i < 4; ++i)
      WL2[i * 256 + tid] = wf2[i * 256 + tid];
  }

  // ---- A_hat K16 B-fragment: B[k=4*lgrp+i][n=lrow]; k=14 row = 1 (bias) ----
  unsigned amx0, amx1;
  {
    float v[4];
    #pragma unroll
    for (int i = 0; i < 4; ++i) {
      const int k = lgrp * 4 + i;
      float s = 0.f;
      if (k == 14) s = 1.f;
      else if (k < 14 && lrow < 14) {
        #pragma unroll
        for (int t = 0; t < 4; ++t)
          if (ADJ_IDX[k][t] == lrow) s += ADJ_W[k][t];
      }
      v[i] = s;
    }
    amx0 = pk2(v[0], v[1]);
    amx1 = pk2(v[2], v[3]);
  }
  const bf16x4 amx = mk4(amx0, amx1);

  unsigned b1inj[8], b2inj[4];
  #pragma unroll
  for (int mt = 0; mt < 8; ++mt) b1inj[mt] = (unsigned)f2b(b1[mt * 16 + lrow]);
  #pragma unroll
  for (int nt = 0; nt < 4; ++nt) b2inj[nt] = (unsigned)f2b(b2[nt * 16 + lrow]);
  const bool isg3 = (lgrp == 3);

  __syncthreads();   // the ONLY block-wide barrier

  const bf16x8* WL1v = (const bf16x8*)WL1;
  const f32x4 zacc = {0.f, 0.f, 0.f, 0.f};

  for (int bi = 0; bi < NPW; ++bi) {
    const int b = bbase + bi;
    if (b >= Btot) break;   // wave-uniform

    // ---------- upfront cvt: raw -> xfw (frees raw for refill) ----------
    unsigned xfw[32];
    #pragma unroll
    for (int i = 0; i < 16; ++i) {
      xfw[2 * i]     = pk2(raw[i].x, raw[i].y);
      xfw[2 * i + 1] = pk2(raw[i].z, raw[i].w);
    }

    // ---------- early prefetch: next batch's loads in flight NOW ----------
    if (bi + 1 < NPW && b + 1 < Btot && lrow < 14) {
      const float* Xp = X + (size_t)(b + 1) * 3584 + lrow * 256 + lgrp * 8;
      #pragma unroll
      for (int kk = 0; kk < 8; ++kk) {
        raw[2 * kk]     = *(const float4*)(Xp + kk * 32);
        raw[2 * kk + 1] = *(const float4*)(Xp + kk * 32 + 4);
      }
    }

    // ---------- GEMM1: G = Xb * W1 (M16 x N128 x K256) ----------
    f32x4 acc1[8];
    #pragma unroll
    for (int nt = 0; nt < 8; ++nt) acc1[nt] = zacc;
    #pragma unroll
    for (int kk = 0; kk < 8; ++kk) {
      uint4 t;
      t.x = xfw[4 * kk]; t.y = xfw[4 * kk + 1];
      t.z = xfw[4 * kk + 2]; t.w = xfw[4 * kk + 3];
      const bf16x8 a = __builtin_bit_cast(bf16x8, t);
      #pragma unroll
      for (int nt = 0; nt < 8; ++nt)
        acc1[nt] = __builtin_amdgcn_mfma_f32_16x16x32_bf16(
            a, WL1v[(nt * 8 + kk) * 64 + lane], acc1[nt], 0, 0, 0);
    }

    // ---------- mix1: H1^T = G^T * Ahat_ext (K=16, lane-local A-frags) ------
    // acc1[mt][j] = G[node=4*lgrp+j][col=16*mt+lrow]  ==  A[row=col][k=node]
    unsigned h1p[8][2];
    #pragma unroll
    for (int mt = 0; mt < 8; ++mt) {
      const unsigned a0 = pk2(acc1[mt][0], acc1[mt][1]);
      const unsigned a1 = isg3 ? b1inj[mt] : pk2(acc1[mt][2], acc1[mt][3]);
      const f32x4 h = MFMA16(mk4(a0, a1), amx, zacc);
      // h[j] = H1[node'=lrow][col=16*mt+4*lgrp+j]; relu + pack
      h1p[mt][0] = pk2(fmaxf(h[0], 0.f), fmaxf(h[1], 0.f));
      h1p[mt][1] = pk2(fmaxf(h[2], 0.f), fmaxf(h[3], 0.f));
    }

    // ---------- GEMM2: C2 = H1 * W2 (M16 x N64 x K128, 8 x K16) -------------
    // A-frag kt2: lane holds H1[lrow][16*kt2+4*lgrp+i]  ==  h1p[kt2] directly.
    f32x4 acc2[4];
    #pragma unroll
    for (int nt = 0; nt < 4; ++nt) acc2[nt] = zacc;
    #pragma unroll
    for (int kp = 0; kp < 4; ++kp) {
      const bf16x4 aE = mk4(h1p[2 * kp][0],     h1p[2 * kp][1]);
      const bf16x4 aO = mk4(h1p[2 * kp + 1][0], h1p[2 * kp + 1][1]);
      #pragma unroll
      for (int nt = 0; nt < 4; ++nt) {
        const uint4 w = WL2[(nt * 4 + kp) * 64 + lane];
        acc2[nt] = MFMA16(aE, mk4(w.x, w.y), acc2[nt]);
        acc2[nt] = MFMA16(aO, mk4(w.z, w.w), acc2[nt]);
      }
    }

    // ---------- mix2: out^T = C2^T * Ahat_ext (+b2 via k=14); store ---------
    // acc2[nt][j] = C2[node=4*lgrp+j][w2col=16*nt+lrow]
    float* outB = out + (size_t)b * 896;
    #pragma unroll
    for (int nt = 0; nt < 4; ++nt) {
      const unsigned a0 = pk2(acc2[nt][0], acc2[nt][1]);
      const unsigned a1 = isg3 ? b2inj[nt] : pk2(acc2[nt][2], acc2[nt][3]);
      const f32x4 o = MFMA16(mk4(a0, a1), amx, zacc);
      // o[j] = out[node=lrow][w2col=16*nt+4*lgrp+j]
      if (lrow < 14) {
        float4 st; st.x = o[0]; st.y = o[1]; st.z = o[2]; st.w = o[3];
        *(float4*)(outB + lrow * 64 + nt * 16 + lgrp * 4) = st;
      }
    }
  }
}

extern "C" void kernel_launch(void* const* d_in, const int* in_sizes, int n_in,
                              void* d_out, int out_size, void* d_ws, size_t ws_size,
                              hipStream_t stream) {
  (void)n_in; (void)out_size; (void)ws_size;
  const float* fea = (const float*)d_in[0];
  const float* W1  = (const float*)d_in[1];
  const float* b1  = (const float*)d_in[2];
  const float* W2  = (const float*)d_in[3];
  const float* b2  = (const float*)d_in[4];
  float* out = (float*)d_out;
  const int Btot = in_sizes[0] / (14 * 256);

  unsigned short* wf = (unsigned short*)d_ws;    // needs 80 KiB of d_ws
  prep_w<<<20, 256, 0, stream>>>(W1, W2, wf);

  const int per_block = 8 * NPW;
  const int grid = (Btot + per_block - 1) / per_block;
  fpm_kernel<<<grid, 512, 0, stream>>>(fea, wf, b1, b2, out, Btot);
}

// Round 10
// 97.607 us; speedup vs baseline: 3.1683x; 1.3194x over previous
//
#include <hip/hip_runtime.h>
#include <hip/hip_bf16.h>

typedef __attribute__((ext_vector_type(8))) short bf16x8;
typedef __attribute__((ext_vector_type(4))) short bf16x4;
typedef __attribute__((ext_vector_type(4))) float f32x4;

#define NPW 4   // batches per wave

#define A3  0.33333334f
#define B4  0.25f
#define C34 0.28867513f

// Per-row sparse A_hat (includes diagonal): up to 4 (neighbor, weight) pairs.
__device__ const int ADJ_IDX[16][4] = {
  {0,1,7,0},{1,0,2,8},{2,1,3,9},{3,2,4,10},
  {4,3,5,11},{5,4,6,12},{6,5,13,0},{7,0,8,0},
  {8,7,9,1},{9,8,10,2},{10,9,11,3},{11,10,12,4},
  {12,11,13,5},{13,12,6,0},{0,0,0,0},{0,0,0,0}
};
__device__ const float ADJ_W[16][4] = {
  {A3,C34,A3,0.f},{B4,C34,B4,B4},{B4,B4,B4,B4},{B4,B4,B4,B4},
  {B4,B4,B4,B4},{B4,B4,C34,B4},{A3,C34,A3,0.f},{A3,A3,C34,0.f},
  {B4,C34,B4,B4},{B4,B4,B4,B4},{B4,B4,B4,B4},{B4,B4,B4,B4},
  {B4,B4,C34,B4},{A3,C34,A3,0.f},{0.f,0.f,0.f,0.f},{0.f,0.f,0.f,0.f}
};

__device__ __forceinline__ unsigned short f2b(float x) {
  unsigned u = __builtin_bit_cast(unsigned, x);
  u += 0x7FFFu + ((u >> 16) & 1u);   // RNE bf16
  return (unsigned short)(u >> 16);
}
// packed f32x2 -> bf16x2 (emits v_cvt_pk_bf16_f32)
__device__ __forceinline__ unsigned pk2(float lo, float hi) {
  float2 t; t.x = lo; t.y = hi;
  __hip_bfloat162 h = __float22bfloat162_rn(t);
  unsigned u; __builtin_memcpy(&u, &h, 4);
  return u;
}
__device__ __forceinline__ bf16x4 mk4(unsigned lo, unsigned hi) {
  uint2 u; u.x = lo; u.y = hi;
  return __builtin_bit_cast(bf16x4, u);
}

#if __has_builtin(__builtin_amdgcn_mfma_f32_16x16x16_bf16)
#define MFMA16(a, b, c) __builtin_amdgcn_mfma_f32_16x16x16_bf16((a), (b), (c), 0, 0, 0)
#elif __has_builtin(__builtin_amdgcn_mfma_f32_16x16x16bf16_1k)
#define MFMA16(a, b, c) __builtin_amdgcn_mfma_f32_16x16x16bf16_1k((a), (b), (c), 0, 0, 0)
#else
__device__ __forceinline__ f32x4 mfma16_asm(bf16x4 a, bf16x4 b, f32x4 c) {
  f32x4 d;
  asm("v_mfma_f32_16x16x16_bf16 %0, %1, %2, %3\n\ts_nop 7\n\ts_nop 7"
      : "=v"(d) : "v"(a), "v"(b), "v"(c));
  return d;
}
#define MFMA16(a, b, c) mfma16_asm((a), (b), (c))
#endif

// ---------- weight prep ----------
// W1 (K=32 B-frags): frag (nt*8+kk); lane holds W1[kk*32+lgrp*8+j][nt*16+lrow],
//   j=0..8 (16B). At wf ushort-offset [0, 32768).
// W2 (K=16 B-frags, PAIRED): uint4 index (nt*4+kp)*64+lane holds frags
//   kt2=2kp (xy) and kt2=2kp+1 (zw): W2[kt2*16+lgrp*4+i][nt*16+lrow], i=0..4.
//   At wf ushort-offset [32768, 40960).  (16 KB table: stays L1-resident.)
__global__ __launch_bounds__(256) void prep_w(
    const float* __restrict__ W1, const float* __restrict__ W2,
    unsigned short* __restrict__ wf)
{
  const int f = blockIdx.x * 256 + threadIdx.x;   // 20 blocks -> 5120
  if (f < 4096) {
    const int lane = f & 63, kk = (f >> 6) & 7, nt = f >> 9;
    const int col = nt * 16 + (lane & 15);
    const int k0  = kk * 32 + (lane >> 4) * 8;
    unsigned short tmp[8];
    #pragma unroll
    for (int j = 0; j < 8; ++j) tmp[j] = f2b(W1[(k0 + j) * 128 + col]);
    *(uint4*)(wf + (size_t)f * 8) = *(const uint4*)tmp;
  } else if (f < 5120) {
    const int f2i = f - 4096;                     // 0..1023
    const int lane = f2i & 63, kp = (f2i >> 6) & 3, nt = f2i >> 8;
    const int col = nt * 16 + (lane & 15);
    const int k0  = kp * 32 + (lane >> 4) * 4;    // kt2=2kp -> k = 2kp*16 + lgrp*4
    uint4 q;
    q.x = (unsigned)f2b(W2[(k0 + 0) * 64 + col]) | ((unsigned)f2b(W2[(k0 + 1) * 64 + col]) << 16);
    q.y = (unsigned)f2b(W2[(k0 + 2) * 64 + col]) | ((unsigned)f2b(W2[(k0 + 3) * 64 + col]) << 16);
    q.z = (unsigned)f2b(W2[(k0 + 16) * 64 + col]) | ((unsigned)f2b(W2[(k0 + 17) * 64 + col]) << 16);
    q.w = (unsigned)f2b(W2[(k0 + 18) * 64 + col]) | ((unsigned)f2b(W2[(k0 + 19) * 64 + col]) << 16);
    *(uint4*)(wf + 32768 + (size_t)f2i * 8) = q;
  }
}

__global__ __launch_bounds__(512) void fpm_kernel(
    const float* __restrict__ X,
    const unsigned short* __restrict__ wf,
    const float* __restrict__ b1, const float* __restrict__ b2,
    float* __restrict__ out, int Btot)
{
  __shared__ __align__(16) uint4 WL1[4096];   // 64 KiB: W1 frags ONLY (2 blocks/CU fit)

  const int tid  = threadIdx.x;
  const int lane = tid & 63;
  const int wv   = tid >> 6;      // 0..7
  const int lrow = lane & 15;
  const int lgrp = lane >> 4;

  const int gw    = blockIdx.x * 8 + wv;
  const int bbase = gw * NPW;

  // ---- issue first batch's X loads ASAP (in flight across LDS fill) ----
  float4 raw[16];
  #pragma unroll
  for (int i = 0; i < 16; ++i) raw[i] = float4{0.f, 0.f, 0.f, 0.f};
  if (bbase < Btot && lrow < 14) {
    const float* Xp = X + (size_t)bbase * 3584 + lrow * 256 + lgrp * 8;
    #pragma unroll
    for (int kk = 0; kk < 8; ++kk) {
      raw[2 * kk]     = *(const float4*)(Xp + kk * 32);
      raw[2 * kk + 1] = *(const float4*)(Xp + kk * 32 + 4);
    }
  }

  // ---- one-time LDS fill of W1 frags (read-only afterwards) ----
  #pragma unroll
  for (int i = 0; i < 8; ++i)
    WL1[i * 512 + tid] = ((const uint4*)wf)[i * 512 + tid];

  // ---- A_hat K16 B-fragment: B[k=4*lgrp+i][n=lrow]; k=14 row = 1 (bias) ----
  unsigned amx0, amx1;
  {
    float v[4];
    #pragma unroll
    for (int i = 0; i < 4; ++i) {
      const int k = lgrp * 4 + i;
      float s = 0.f;
      if (k == 14) s = 1.f;
      else if (k < 14 && lrow < 14) {
        #pragma unroll
        for (int t = 0; t < 4; ++t)
          if (ADJ_IDX[k][t] == lrow) s += ADJ_W[k][t];
      }
      v[i] = s;
    }
    amx0 = pk2(v[0], v[1]);
    amx1 = pk2(v[2], v[3]);
  }
  const bf16x4 amx = mk4(amx0, amx1);

  unsigned b1inj[8], b2inj[4];
  #pragma unroll
  for (int mt = 0; mt < 8; ++mt) b1inj[mt] = (unsigned)f2b(b1[mt * 16 + lrow]);
  #pragma unroll
  for (int nt = 0; nt < 4; ++nt) b2inj[nt] = (unsigned)f2b(b2[nt * 16 + lrow]);
  const bool isg3 = (lgrp == 3);

  __syncthreads();   // the ONLY block-wide barrier

  // ---- de-convoy: skew wave phases so co-resident waves occupy different
  //      pipes (LDS / MFMA / VALU / HBM) instead of moving in lockstep ----
  #pragma unroll
  for (int i = 0; i < 7; ++i)
    if (i < wv) asm volatile("s_sleep 4" :::);

  const bf16x8* WL1v = (const bf16x8*)WL1;
  const uint4*  W2g  = (const uint4*)(wf + 32768);   // L1-hot 16 KB table
  const f32x4 zacc = {0.f, 0.f, 0.f, 0.f};

  for (int bi = 0; bi < NPW; ++bi) {
    const int b = bbase + bi;
    if (b >= Btot) break;   // wave-uniform

    // ---------- GEMM1: G = Xb * W1 (M16 x N128 x K256), per-kk cvt ----------
    f32x4 acc1[8];
    #pragma unroll
    for (int nt = 0; nt < 8; ++nt) acc1[nt] = zacc;
    #pragma unroll
    for (int kk = 0; kk < 8; ++kk) {
      uint4 t;
      t.x = pk2(raw[2 * kk].x,     raw[2 * kk].y);
      t.y = pk2(raw[2 * kk].z,     raw[2 * kk].w);
      t.z = pk2(raw[2 * kk + 1].x, raw[2 * kk + 1].y);
      t.w = pk2(raw[2 * kk + 1].z, raw[2 * kk + 1].w);
      const bf16x8 a = __builtin_bit_cast(bf16x8, t);
      #pragma unroll
      for (int nt = 0; nt < 8; ++nt)
        acc1[nt] = __builtin_amdgcn_mfma_f32_16x16x32_bf16(
            a, WL1v[(nt * 8 + kk) * 64 + lane], acc1[nt], 0, 0, 0);
    }

    // ---------- prefetch next batch (raw fully consumed above) ----------
    if (bi + 1 < NPW && b + 1 < Btot && lrow < 14) {
      const float* Xp = X + (size_t)(b + 1) * 3584 + lrow * 256 + lgrp * 8;
      #pragma unroll
      for (int kk = 0; kk < 8; ++kk) {
        raw[2 * kk]     = *(const float4*)(Xp + kk * 32);
        raw[2 * kk + 1] = *(const float4*)(Xp + kk * 32 + 4);
      }
    }

    // ---------- mix1: H1^T = G^T * Ahat_ext (K=16, lane-local A-frags) ------
    // acc1[mt][j] = G[node=4*lgrp+j][col=16*mt+lrow]  ==  A[row=col][k=node]
    unsigned h1p[8][2];
    #pragma unroll
    for (int mt = 0; mt < 8; ++mt) {
      const unsigned a0 = pk2(acc1[mt][0], acc1[mt][1]);
      const unsigned a1 = isg3 ? b1inj[mt] : pk2(acc1[mt][2], acc1[mt][3]);
      const f32x4 h = MFMA16(mk4(a0, a1), amx, zacc);
      // h[j] = H1[node'=lrow][col=16*mt+4*lgrp+j]; relu + pack
      h1p[mt][0] = pk2(fmaxf(h[0], 0.f), fmaxf(h[1], 0.f));
      h1p[mt][1] = pk2(fmaxf(h[2], 0.f), fmaxf(h[3], 0.f));
    }

    // ---------- GEMM2: C2 = H1 * W2 (M16 x N64 x K128); W2 from L1 ----------
    // A-frag kt2: lane holds H1[lrow][16*kt2+4*lgrp+i]  ==  h1p[kt2] directly.
    f32x4 acc2[4];
    #pragma unroll
    for (int nt = 0; nt < 4; ++nt) acc2[nt] = zacc;
    #pragma unroll
    for (int kp = 0; kp < 4; ++kp) {
      const bf16x4 aE = mk4(h1p[2 * kp][0],     h1p[2 * kp][1]);
      const bf16x4 aO = mk4(h1p[2 * kp + 1][0], h1p[2 * kp + 1][1]);
      #pragma unroll
      for (int nt = 0; nt < 4; ++nt) {
        const uint4 w = W2g[(nt * 4 + kp) * 64 + lane];
        acc2[nt] = MFMA16(aE, mk4(w.x, w.y), acc2[nt]);
        acc2[nt] = MFMA16(aO, mk4(w.z, w.w), acc2[nt]);
      }
    }

    // ---------- mix2: out^T = C2^T * Ahat_ext (+b2 via k=14); store ---------
    // acc2[nt][j] = C2[node=4*lgrp+j][w2col=16*nt+lrow]
    float* outB = out + (size_t)b * 896;
    #pragma unroll
    for (int nt = 0; nt < 4; ++nt) {
      const unsigned a0 = pk2(acc2[nt][0], acc2[nt][1]);
      const unsigned a1 = isg3 ? b2inj[nt] : pk2(acc2[nt][2], acc2[nt][3]);
      const f32x4 o = MFMA16(mk4(a0, a1), amx, zacc);
      // o[j] = out[node=lrow][w2col=16*nt+4*lgrp+j]
      if (lrow < 14) {
        float4 st; st.x = o[0]; st.y = o[1]; st.z = o[2]; st.w = o[3];
        *(float4*)(outB + lrow * 64 + nt * 16 + lgrp * 4) = st;
      }
    }
  }
}

extern "C" void kernel_launch(void* const* d_in, const int* in_sizes, int n_in,
                              void* d_out, int out_size, void* d_ws, size_t ws_size,
                              hipStream_t stream) {
  (void)n_in; (void)out_size; (void)ws_size;
  const float* fea = (const float*)d_in[0];
  const float* W1  = (const float*)d_in[1];
  const float* b1  = (const float*)d_in[2];
  const float* W2  = (const float*)d_in[3];
  const float* b2  = (const float*)d_in[4];
  float* out = (float*)d_out;
  const int Btot = in_sizes[0] / (14 * 256);

  unsigned short* wf = (unsigned short*)d_ws;    // needs 80 KiB of d_ws
  prep_w<<<20, 256, 0, stream>>>(W1, W2, wf);

  const int per_block = 8 * NPW;
  const int grid = (Btot + per_block - 1) / per_block;
  fpm_kernel<<<grid, 512, 0, stream>>>(fea, wf, b1, b2, out, Btot);
}

// Round 11
// 69.267 us; speedup vs baseline: 4.4645x; 1.4091x over previous
//
#include <hip/hip_runtime.h>
#include <hip/hip_bf16.h>

typedef __attribute__((ext_vector_type(8))) short bf16x8;
typedef __attribute__((ext_vector_type(4))) short bf16x4;
typedef __attribute__((ext_vector_type(4))) float f32x4;

#define NPW 4   // batches per wave

#define A3  0.33333334f
#define B4  0.25f
#define C34 0.28867513f

// Per-row sparse A_hat (includes diagonal): up to 4 (neighbor, weight) pairs.
__device__ const int ADJ_IDX[16][4] = {
  {0,1,7,0},{1,0,2,8},{2,1,3,9},{3,2,4,10},
  {4,3,5,11},{5,4,6,12},{6,5,13,0},{7,0,8,0},
  {8,7,9,1},{9,8,10,2},{10,9,11,3},{11,10,12,4},
  {12,11,13,5},{13,12,6,0},{0,0,0,0},{0,0,0,0}
};
__device__ const float ADJ_W[16][4] = {
  {A3,C34,A3,0.f},{B4,C34,B4,B4},{B4,B4,B4,B4},{B4,B4,B4,B4},
  {B4,B4,B4,B4},{B4,B4,C34,B4},{A3,C34,A3,0.f},{A3,A3,C34,0.f},
  {B4,C34,B4,B4},{B4,B4,B4,B4},{B4,B4,B4,B4},{B4,B4,B4,B4},
  {B4,B4,C34,B4},{A3,C34,A3,0.f},{0.f,0.f,0.f,0.f},{0.f,0.f,0.f,0.f}
};

__device__ __forceinline__ unsigned short f2b(float x) {
  unsigned u = __builtin_bit_cast(unsigned, x);
  u += 0x7FFFu + ((u >> 16) & 1u);   // RNE bf16
  return (unsigned short)(u >> 16);
}
// packed f32x2 -> bf16x2 (emits v_cvt_pk_bf16_f32)
__device__ __forceinline__ unsigned pk2(float lo, float hi) {
  float2 t; t.x = lo; t.y = hi;
  __hip_bfloat162 h = __float22bfloat162_rn(t);
  unsigned u; __builtin_memcpy(&u, &h, 4);
  return u;
}
__device__ __forceinline__ bf16x4 mk4(unsigned lo, unsigned hi) {
  uint2 u; u.x = lo; u.y = hi;
  return __builtin_bit_cast(bf16x4, u);
}

#if __has_builtin(__builtin_amdgcn_mfma_f32_16x16x16_bf16)
#define MFMA16(a, b, c) __builtin_amdgcn_mfma_f32_16x16x16_bf16((a), (b), (c), 0, 0, 0)
#elif __has_builtin(__builtin_amdgcn_mfma_f32_16x16x16bf16_1k)
#define MFMA16(a, b, c) __builtin_amdgcn_mfma_f32_16x16x16bf16_1k((a), (b), (c), 0, 0, 0)
#else
__device__ __forceinline__ f32x4 mfma16_asm(bf16x4 a, bf16x4 b, f32x4 c) {
  f32x4 d;
  asm("v_mfma_f32_16x16x16_bf16 %0, %1, %2, %3\n\ts_nop 7\n\ts_nop 7"
      : "=v"(d) : "v"(a), "v"(b), "v"(c));
  return d;
}
#define MFMA16(a, b, c) mfma16_asm((a), (b), (c))
#endif

#define SBAR() __builtin_amdgcn_sched_barrier(0)

// ---------- weight prep ----------
// W1 (K=32 B-frags): frag (nt*8+kk); lane holds W1[kk*32+lgrp*8+j][nt*16+lrow],
//   j=0..8 (16B). At wf ushort-offset [0, 32768).
// W2 (K=16 B-frags, PAIRED): uint4 index (nt*4+kp)*64+lane holds frags
//   kt2=2kp (xy) and kt2=2kp+1 (zw): W2[kt2*16+lgrp*4+i][nt*16+lrow], i=0..4.
//   At wf ushort-offset [32768, 40960).
__global__ __launch_bounds__(256) void prep_w(
    const float* __restrict__ W1, const float* __restrict__ W2,
    unsigned short* __restrict__ wf)
{
  const int f = blockIdx.x * 256 + threadIdx.x;   // 20 blocks -> 5120
  if (f < 4096) {
    const int lane = f & 63, kk = (f >> 6) & 7, nt = f >> 9;
    const int col = nt * 16 + (lane & 15);
    const int k0  = kk * 32 + (lane >> 4) * 8;
    unsigned short tmp[8];
    #pragma unroll
    for (int j = 0; j < 8; ++j) tmp[j] = f2b(W1[(k0 + j) * 128 + col]);
    *(uint4*)(wf + (size_t)f * 8) = *(const uint4*)tmp;
  } else if (f < 5120) {
    const int f2i = f - 4096;                     // 0..1023
    const int lane = f2i & 63, kp = (f2i >> 6) & 3, nt = f2i >> 8;
    const int col = nt * 16 + (lane & 15);
    const int k0  = kp * 32 + (lane >> 4) * 4;    // kt2=2kp -> k = 2kp*16 + lgrp*4
    uint4 q;
    q.x = (unsigned)f2b(W2[(k0 + 0) * 64 + col]) | ((unsigned)f2b(W2[(k0 + 1) * 64 + col]) << 16);
    q.y = (unsigned)f2b(W2[(k0 + 2) * 64 + col]) | ((unsigned)f2b(W2[(k0 + 3) * 64 + col]) << 16);
    q.z = (unsigned)f2b(W2[(k0 + 16) * 64 + col]) | ((unsigned)f2b(W2[(k0 + 17) * 64 + col]) << 16);
    q.w = (unsigned)f2b(W2[(k0 + 18) * 64 + col]) | ((unsigned)f2b(W2[(k0 + 19) * 64 + col]) << 16);
    *(uint4*)(wf + 32768 + (size_t)f2i * 8) = q;
  }
}

__global__ __launch_bounds__(512) void fpm_kernel(
    const float* __restrict__ X,
    const unsigned short* __restrict__ wf,
    const float* __restrict__ b1, const float* __restrict__ b2,
    float* __restrict__ out, int Btot)
{
  __shared__ __align__(16) uint4 WL1[4096];   // 64 KiB W1 frags
  __shared__ __align__(16) uint4 WL2[1024];   // 16 KiB paired W2 frags

  const int tid  = threadIdx.x;
  const int lane = tid & 63;
  const int wv   = tid >> 6;      // 0..7
  const int lrow = lane & 15;
  const int lgrp = lane >> 4;

  const int gw    = blockIdx.x * 8 + wv;
  const int bbase = gw * NPW;

  // ---- issue first batch's X loads ASAP (in flight across LDS fill) ----
  float4 raw[16];
  #pragma unroll
  for (int i = 0; i < 16; ++i) raw[i] = float4{0.f, 0.f, 0.f, 0.f};
  const bool ld_ok = (bbase < Btot) && (lrow < 14);
  if (ld_ok) {
    const float* Xp = X + (size_t)bbase * 3584 + lrow * 256 + lgrp * 8;
    #pragma unroll
    for (int kk = 0; kk < 8; ++kk) {
      raw[2 * kk]     = *(const float4*)(Xp + kk * 32);
      raw[2 * kk + 1] = *(const float4*)(Xp + kk * 32 + 4);
    }
  }

  // ---- one-time LDS fill (read-only afterwards) ----
  #pragma unroll
  for (int i = 0; i < 8; ++i)
    WL1[i * 512 + tid] = ((const uint4*)wf)[i * 512 + tid];
  if (tid < 256) {
    const uint4* wf2 = (const uint4*)(wf + 32768);
    #pragma unroll
    for (int i = 0; i < 4; ++i)
      WL2[i * 256 + tid] = wf2[i * 256 + tid];
  }

  // ---- A_hat K16 B-fragment: B[k=4*lgrp+i][n=lrow]; k=14 row = 1 (bias) ----
  unsigned amx0, amx1;
  {
    float v[4];
    #pragma unroll
    for (int i = 0; i < 4; ++i) {
      const int k = lgrp * 4 + i;
      float s = 0.f;
      if (k == 14) s = 1.f;
      else if (k < 14 && lrow < 14) {
        #pragma unroll
        for (int t = 0; t < 4; ++t)
          if (ADJ_IDX[k][t] == lrow) s += ADJ_W[k][t];
      }
      v[i] = s;
    }
    amx0 = pk2(v[0], v[1]);
    amx1 = pk2(v[2], v[3]);
  }
  const bf16x4 amx = mk4(amx0, amx1);

  unsigned b1inj[8], b2inj[4];
  #pragma unroll
  for (int mt = 0; mt < 8; ++mt) b1inj[mt] = (unsigned)f2b(b1[mt * 16 + lrow]);
  #pragma unroll
  for (int nt = 0; nt < 4; ++nt) b2inj[nt] = (unsigned)f2b(b2[nt * 16 + lrow]);
  const bool isg3 = (lgrp == 3);

  __syncthreads();   // the ONLY block-wide barrier

  const bf16x8* WL1v = (const bf16x8*)WL1;
  const f32x4 zacc = {0.f, 0.f, 0.f, 0.f};

  for (int bi = 0; bi < NPW; ++bi) {
    const int b = bbase + bi;
    if (b >= Btot) break;   // wave-uniform
    const bool pf = (bi + 1 < NPW) && (b + 1 < Btot) && (lrow < 14);
    const float* Xn = X + (size_t)(b + 1) * 3584 + lrow * 256 + lgrp * 8;

    // ---------- upfront cvt: raw -> xfw (raw dies; 32 packed regs) ----------
    unsigned xfw[32];
    #pragma unroll
    for (int i = 0; i < 16; ++i) {
      xfw[2 * i]     = pk2(raw[i].x, raw[i].y);
      xfw[2 * i + 1] = pk2(raw[i].z, raw[i].w);
    }
    SBAR();
    // ---- prefetch quarter 1 (raw[0..3]): ~1200 cy cover ----
    if (pf) {
      raw[0] = *(const float4*)(Xn);       raw[1] = *(const float4*)(Xn + 4);
      raw[2] = *(const float4*)(Xn + 32);  raw[3] = *(const float4*)(Xn + 36);
    }
    SBAR();

    // ---------- GEMM1: G = Xb * W1 (M16 x N128 x K256) ----------
    f32x4 acc1[8];
    #pragma unroll
    for (int nt = 0; nt < 8; ++nt) acc1[nt] = zacc;
    __builtin_amdgcn_s_setprio(1);
    #pragma unroll
    for (int kk = 0; kk < 8; ++kk) {
      uint4 t;
      t.x = xfw[4 * kk];     t.y = xfw[4 * kk + 1];
      t.z = xfw[4 * kk + 2]; t.w = xfw[4 * kk + 3];
      const bf16x8 a = __builtin_bit_cast(bf16x8, t);
      #pragma unroll
      for (int nt = 0; nt < 8; ++nt)
        acc1[nt] = __builtin_amdgcn_mfma_f32_16x16x32_bf16(
            a, WL1v[(nt * 8 + kk) * 64 + lane], acc1[nt], 0, 0, 0);
    }
    __builtin_amdgcn_s_setprio(0);
    SBAR();
    // ---- prefetch quarter 2 (raw[4..7]) ----
    if (pf) {
      raw[4] = *(const float4*)(Xn + 64);  raw[5] = *(const float4*)(Xn + 68);
      raw[6] = *(const float4*)(Xn + 96);  raw[7] = *(const float4*)(Xn + 100);
    }
    SBAR();

    // ---------- mix1: H1^T = G^T * Ahat_ext (K=16, lane-local A-frags) ------
    // acc1[mt][j] = G[node=4*lgrp+j][col=16*mt+lrow]  ==  A[row=col][k=node]
    unsigned h1p[8][2];
    #pragma unroll
    for (int mt = 0; mt < 8; ++mt) {
      const unsigned a0 = pk2(acc1[mt][0], acc1[mt][1]);
      const unsigned a1 = isg3 ? b1inj[mt] : pk2(acc1[mt][2], acc1[mt][3]);
      const f32x4 h = MFMA16(mk4(a0, a1), amx, zacc);
      // h[j] = H1[node'=lrow][col=16*mt+4*lgrp+j]; relu + pack
      h1p[mt][0] = pk2(fmaxf(h[0], 0.f), fmaxf(h[1], 0.f));
      h1p[mt][1] = pk2(fmaxf(h[2], 0.f), fmaxf(h[3], 0.f));
    }
    SBAR();
    // ---- prefetch quarter 3 (raw[8..11]) ----
    if (pf) {
      raw[8]  = *(const float4*)(Xn + 128); raw[9]  = *(const float4*)(Xn + 132);
      raw[10] = *(const float4*)(Xn + 160); raw[11] = *(const float4*)(Xn + 164);
    }
    SBAR();

    // ---------- GEMM2: C2 = H1 * W2 (M16 x N64 x K128, 8 x K16) -------------
    // A-frag kt2: lane holds H1[lrow][16*kt2+4*lgrp+i]  ==  h1p[kt2] directly.
    f32x4 acc2[4];
    #pragma unroll
    for (int nt = 0; nt < 4; ++nt) acc2[nt] = zacc;
    __builtin_amdgcn_s_setprio(1);
    #pragma unroll
    for (int kp = 0; kp < 4; ++kp) {
      const bf16x4 aE = mk4(h1p[2 * kp][0],     h1p[2 * kp][1]);
      const bf16x4 aO = mk4(h1p[2 * kp + 1][0], h1p[2 * kp + 1][1]);
      #pragma unroll
      for (int nt = 0; nt < 4; ++nt) {
        const uint4 w = WL2[(nt * 4 + kp) * 64 + lane];
        acc2[nt] = MFMA16(aE, mk4(w.x, w.y), acc2[nt]);
        acc2[nt] = MFMA16(aO, mk4(w.z, w.w), acc2[nt]);
      }
    }
    __builtin_amdgcn_s_setprio(0);
    SBAR();
    // ---- prefetch quarter 4 (raw[12..15]) ----
    if (pf) {
      raw[12] = *(const float4*)(Xn + 192); raw[13] = *(const float4*)(Xn + 196);
      raw[14] = *(const float4*)(Xn + 224); raw[15] = *(const float4*)(Xn + 228);
    }
    SBAR();

    // ---------- mix2: out^T = C2^T * Ahat_ext (+b2 via k=14); store ---------
    // acc2[nt][j] = C2[node=4*lgrp+j][w2col=16*nt+lrow]
    float* outB = out + (size_t)b * 896;
    #pragma unroll
    for (int nt = 0; nt < 4; ++nt) {
      const unsigned a0 = pk2(acc2[nt][0], acc2[nt][1]);
      const unsigned a1 = isg3 ? b2inj[nt] : pk2(acc2[nt][2], acc2[nt][3]);
      const f32x4 o = MFMA16(mk4(a0, a1), amx, zacc);
      // o[j] = out[node=lrow][w2col=16*nt+4*lgrp+j]
      if (lrow < 14) {
        float4 st; st.x = o[0]; st.y = o[1]; st.z = o[2]; st.w = o[3];
        *(float4*)(outB + lrow * 64 + nt * 16 + lgrp * 4) = st;
      }
    }
  }
}

extern "C" void kernel_launch(void* const* d_in, const int* in_sizes, int n_in,
                              void* d_out, int out_size, void* d_ws, size_t ws_size,
                              hipStream_t stream) {
  (void)n_in; (void)out_size; (void)ws_size;
  const float* fea = (const float*)d_in[0];
  const float* W1  = (const float*)d_in[1];
  const float* b1  = (const float*)d_in[2];
  const float* W2  = (const float*)d_in[3];
  const float* b2  = (const float*)d_in[4];
  float* out = (float*)d_out;
  const int Btot = in_sizes[0] / (14 * 256);

  unsigned short* wf = (unsigned short*)d_ws;    // needs 80 KiB of d_ws
  prep_w<<<20, 256, 0, stream>>>(W1, W2, wf);

  const int per_block = 8 * NPW;
  const int grid = (Btot + per_block - 1) / per_block;
  fpm_kernel<<<grid, 512, 0, stream>>>(fea, wf, b1, b2, out, Btot);
}

// Round 12
// 69.038 us; speedup vs baseline: 4.4794x; 1.0033x over previous
//
#include <hip/hip_runtime.h>
#include <hip/hip_bf16.h>

typedef __attribute__((ext_vector_type(8))) short bf16x8;
typedef __attribute__((ext_vector_type(4))) short bf16x4;
typedef __attribute__((ext_vector_type(4))) float f32x4;

#define NPW 4   // batches per wave

#define A3  0.33333334f
#define B4  0.25f
#define C34 0.28867513f

// Per-row sparse A_hat (includes diagonal): up to 4 (neighbor, weight) pairs.
__device__ const int ADJ_IDX[16][4] = {
  {0,1,7,0},{1,0,2,8},{2,1,3,9},{3,2,4,10},
  {4,3,5,11},{5,4,6,12},{6,5,13,0},{7,0,8,0},
  {8,7,9,1},{9,8,10,2},{10,9,11,3},{11,10,12,4},
  {12,11,13,5},{13,12,6,0},{0,0,0,0},{0,0,0,0}
};
__device__ const float ADJ_W[16][4] = {
  {A3,C34,A3,0.f},{B4,C34,B4,B4},{B4,B4,B4,B4},{B4,B4,B4,B4},
  {B4,B4,B4,B4},{B4,B4,C34,B4},{A3,C34,A3,0.f},{A3,A3,C34,0.f},
  {B4,C34,B4,B4},{B4,B4,B4,B4},{B4,B4,B4,B4},{B4,B4,B4,B4},
  {B4,B4,C34,B4},{A3,C34,A3,0.f},{0.f,0.f,0.f,0.f},{0.f,0.f,0.f,0.f}
};

__device__ __forceinline__ unsigned short f2b(float x) {
  unsigned u = __builtin_bit_cast(unsigned, x);
  u += 0x7FFFu + ((u >> 16) & 1u);   // RNE bf16
  return (unsigned short)(u >> 16);
}
// packed f32x2 -> bf16x2 (emits v_cvt_pk_bf16_f32)
__device__ __forceinline__ unsigned pk2(float lo, float hi) {
  float2 t; t.x = lo; t.y = hi;
  __hip_bfloat162 h = __float22bfloat162_rn(t);
  unsigned u; __builtin_memcpy(&u, &h, 4);
  return u;
}
__device__ __forceinline__ bf16x4 mk4(unsigned lo, unsigned hi) {
  uint2 u; u.x = lo; u.y = hi;
  return __builtin_bit_cast(bf16x4, u);
}

#if __has_builtin(__builtin_amdgcn_mfma_f32_16x16x16_bf16)
#define MFMA16(a, b, c) __builtin_amdgcn_mfma_f32_16x16x16_bf16((a), (b), (c), 0, 0, 0)
#elif __has_builtin(__builtin_amdgcn_mfma_f32_16x16x16bf16_1k)
#define MFMA16(a, b, c) __builtin_amdgcn_mfma_f32_16x16x16bf16_1k((a), (b), (c), 0, 0, 0)
#else
__device__ __forceinline__ f32x4 mfma16_asm(bf16x4 a, bf16x4 b, f32x4 c) {
  f32x4 d;
  asm("v_mfma_f32_16x16x16_bf16 %0, %1, %2, %3\n\ts_nop 7\n\ts_nop 7"
      : "=v"(d) : "v"(a), "v"(b), "v"(c));
  return d;
}
#define MFMA16(a, b, c) mfma16_asm((a), (b), (c))
#endif

#define SBAR() __builtin_amdgcn_sched_barrier(0)

// ---------- weight prep ----------
// W1 (K=32 B-frags): frag (nt*8+kk); lane holds W1[kk*32+lgrp*8+j][nt*16+lrow],
//   j=0..8 (16B). At wf ushort-offset [0, 32768).
// W2 (K=16 B-frags, PAIRED): uint4 index (nt*4+kp)*64+lane holds frags
//   kt2=2kp (xy) and kt2=2kp+1 (zw): W2[kt2*16+lgrp*4+i][nt*16+lrow], i=0..4.
//   At wf ushort-offset [32768, 40960).
__global__ __launch_bounds__(256) void prep_w(
    const float* __restrict__ W1, const float* __restrict__ W2,
    unsigned short* __restrict__ wf)
{
  const int f = blockIdx.x * 256 + threadIdx.x;   // 20 blocks -> 5120
  if (f < 4096) {
    const int lane = f & 63, kk = (f >> 6) & 7, nt = f >> 9;
    const int col = nt * 16 + (lane & 15);
    const int k0  = kk * 32 + (lane >> 4) * 8;
    unsigned short tmp[8];
    #pragma unroll
    for (int j = 0; j < 8; ++j) tmp[j] = f2b(W1[(k0 + j) * 128 + col]);
    *(uint4*)(wf + (size_t)f * 8) = *(const uint4*)tmp;
  } else if (f < 5120) {
    const int f2i = f - 4096;                     // 0..1023
    const int lane = f2i & 63, kp = (f2i >> 6) & 3, nt = f2i >> 8;
    const int col = nt * 16 + (lane & 15);
    const int k0  = kp * 32 + (lane >> 4) * 4;    // kt2=2kp -> k = 2kp*16 + lgrp*4
    uint4 q;
    q.x = (unsigned)f2b(W2[(k0 + 0) * 64 + col]) | ((unsigned)f2b(W2[(k0 + 1) * 64 + col]) << 16);
    q.y = (unsigned)f2b(W2[(k0 + 2) * 64 + col]) | ((unsigned)f2b(W2[(k0 + 3) * 64 + col]) << 16);
    q.z = (unsigned)f2b(W2[(k0 + 16) * 64 + col]) | ((unsigned)f2b(W2[(k0 + 17) * 64 + col]) << 16);
    q.w = (unsigned)f2b(W2[(k0 + 18) * 64 + col]) | ((unsigned)f2b(W2[(k0 + 19) * 64 + col]) << 16);
    *(uint4*)(wf + 32768 + (size_t)f2i * 8) = q;
  }
}

__global__ __launch_bounds__(512) void fpm_kernel(
    const float* __restrict__ X,
    const unsigned short* __restrict__ wf,
    const float* __restrict__ b1, const float* __restrict__ b2,
    float* __restrict__ out, int Btot)
{
  __shared__ __align__(16) uint4 WL1[4096];   // 64 KiB W1 frags
  __shared__ __align__(16) uint4 WL2[1024];   // 16 KiB paired W2 frags

  const int tid  = threadIdx.x;
  const int lane = tid & 63;
  const int wv   = tid >> 6;      // 0..7
  const int lrow = lane & 15;
  const int lgrp = lane >> 4;

  const int gw    = blockIdx.x * 8 + wv;
  const int bbase = gw * NPW;

  // ---- issue first batch's X loads ASAP (in flight across LDS fill) ----
  float4 raw[16];
  #pragma unroll
  for (int i = 0; i < 16; ++i) raw[i] = float4{0.f, 0.f, 0.f, 0.f};
  const bool ld_ok = (bbase < Btot) && (lrow < 14);
  if (ld_ok) {
    const float* Xp = X + (size_t)bbase * 3584 + lrow * 256 + lgrp * 8;
    #pragma unroll
    for (int kk = 0; kk < 8; ++kk) {
      raw[2 * kk]     = *(const float4*)(Xp + kk * 32);
      raw[2 * kk + 1] = *(const float4*)(Xp + kk * 32 + 4);
    }
  }

  // ---- one-time LDS fill (read-only afterwards) ----
  #pragma unroll
  for (int i = 0; i < 8; ++i)
    WL1[i * 512 + tid] = ((const uint4*)wf)[i * 512 + tid];
  if (tid < 256) {
    const uint4* wf2 = (const uint4*)(wf + 32768);
    #pragma unroll
    for (int i = 0; i < 4; ++i)
      WL2[i * 256 + tid] = wf2[i * 256 + tid];
  }

  // ---- A_hat K16 B-fragment: B[k=4*lgrp+i][n=lrow]; k=14 row = 1 (bias) ----
  unsigned amx0, amx1;
  {
    float v[4];
    #pragma unroll
    for (int i = 0; i < 4; ++i) {
      const int k = lgrp * 4 + i;
      float s = 0.f;
      if (k == 14) s = 1.f;
      else if (k < 14 && lrow < 14) {
        #pragma unroll
        for (int t = 0; t < 4; ++t)
          if (ADJ_IDX[k][t] == lrow) s += ADJ_W[k][t];
      }
      v[i] = s;
    }
    amx0 = pk2(v[0], v[1]);
    amx1 = pk2(v[2], v[3]);
  }
  const bf16x4 amx = mk4(amx0, amx1);

  unsigned b1inj[8], b2inj[4];
  #pragma unroll
  for (int mt = 0; mt < 8; ++mt) b1inj[mt] = (unsigned)f2b(b1[mt * 16 + lrow]);
  #pragma unroll
  for (int nt = 0; nt < 4; ++nt) b2inj[nt] = (unsigned)f2b(b2[nt * 16 + lrow]);
  const bool isg3 = (lgrp == 3);

  __syncthreads();   // the ONLY block-wide barrier

  // ---- de-convoy (ISOLATED test this round): skew wave start phases so
  //      co-resident waves occupy different pipes (LDS / MFMA / VALU / HBM)
  //      instead of bursting the same pipe in lockstep. ~384 cy per step,
  //      wave-uniform branch, one-time cost amortized over NPW batches. ----
  #pragma unroll
  for (int i = 0; i < 7; ++i)
    if (i < wv) asm volatile("s_sleep 6" :::);

  const bf16x8* WL1v = (const bf16x8*)WL1;
  const f32x4 zacc = {0.f, 0.f, 0.f, 0.f};

  for (int bi = 0; bi < NPW; ++bi) {
    const int b = bbase + bi;
    if (b >= Btot) break;   // wave-uniform
    const bool pf = (bi + 1 < NPW) && (b + 1 < Btot) && (lrow < 14);
    const float* Xn = X + (size_t)(b + 1) * 3584 + lrow * 256 + lgrp * 8;

    // ---------- upfront cvt: raw -> xfw (raw dies; 32 packed regs) ----------
    unsigned xfw[32];
    #pragma unroll
    for (int i = 0; i < 16; ++i) {
      xfw[2 * i]     = pk2(raw[i].x, raw[i].y);
      xfw[2 * i + 1] = pk2(raw[i].z, raw[i].w);
    }
    SBAR();
    // ---- prefetch quarter 1 (raw[0..3]): ~1200 cy cover ----
    if (pf) {
      raw[0] = *(const float4*)(Xn);       raw[1] = *(const float4*)(Xn + 4);
      raw[2] = *(const float4*)(Xn + 32);  raw[3] = *(const float4*)(Xn + 36);
    }
    SBAR();

    // ---------- GEMM1: G = Xb * W1 (M16 x N128 x K256) ----------
    f32x4 acc1[8];
    #pragma unroll
    for (int nt = 0; nt < 8; ++nt) acc1[nt] = zacc;
    __builtin_amdgcn_s_setprio(1);
    #pragma unroll
    for (int kk = 0; kk < 8; ++kk) {
      uint4 t;
      t.x = xfw[4 * kk];     t.y = xfw[4 * kk + 1];
      t.z = xfw[4 * kk + 2]; t.w = xfw[4 * kk + 3];
      const bf16x8 a = __builtin_bit_cast(bf16x8, t);
      #pragma unroll
      for (int nt = 0; nt < 8; ++nt)
        acc1[nt] = __builtin_amdgcn_mfma_f32_16x16x32_bf16(
            a, WL1v[(nt * 8 + kk) * 64 + lane], acc1[nt], 0, 0, 0);
    }
    __builtin_amdgcn_s_setprio(0);
    SBAR();
    // ---- prefetch quarter 2 (raw[4..7]) ----
    if (pf) {
      raw[4] = *(const float4*)(Xn + 64);  raw[5] = *(const float4*)(Xn + 68);
      raw[6] = *(const float4*)(Xn + 96);  raw[7] = *(const float4*)(Xn + 100);
    }
    SBAR();

    // ---------- mix1: H1^T = G^T * Ahat_ext (K=16, lane-local A-frags) ------
    // acc1[mt][j] = G[node=4*lgrp+j][col=16*mt+lrow]  ==  A[row=col][k=node]
    unsigned h1p[8][2];
    #pragma unroll
    for (int mt = 0; mt < 8; ++mt) {
      const unsigned a0 = pk2(acc1[mt][0], acc1[mt][1]);
      const unsigned a1 = isg3 ? b1inj[mt] : pk2(acc1[mt][2], acc1[mt][3]);
      const f32x4 h = MFMA16(mk4(a0, a1), amx, zacc);
      // h[j] = H1[node'=lrow][col=16*mt+4*lgrp+j]; relu + pack
      h1p[mt][0] = pk2(fmaxf(h[0], 0.f), fmaxf(h[1], 0.f));
      h1p[mt][1] = pk2(fmaxf(h[2], 0.f), fmaxf(h[3], 0.f));
    }
    SBAR();
    // ---- prefetch quarter 3 (raw[8..11]) ----
    if (pf) {
      raw[8]  = *(const float4*)(Xn + 128); raw[9]  = *(const float4*)(Xn + 132);
      raw[10] = *(const float4*)(Xn + 160); raw[11] = *(const float4*)(Xn + 164);
    }
    SBAR();

    // ---------- GEMM2: C2 = H1 * W2 (M16 x N64 x K128, 8 x K16) -------------
    // A-frag kt2: lane holds H1[lrow][16*kt2+4*lgrp+i]  ==  h1p[kt2] directly.
    f32x4 acc2[4];
    #pragma unroll
    for (int nt = 0; nt < 4; ++nt) acc2[nt] = zacc;
    __builtin_amdgcn_s_setprio(1);
    #pragma unroll
    for (int kp = 0; kp < 4; ++kp) {
      const bf16x4 aE = mk4(h1p[2 * kp][0],     h1p[2 * kp][1]);
      const bf16x4 aO = mk4(h1p[2 * kp + 1][0], h1p[2 * kp + 1][1]);
      #pragma unroll
      for (int nt = 0; nt < 4; ++nt) {
        const uint4 w = WL2[(nt * 4 + kp) * 64 + lane];
        acc2[nt] = MFMA16(aE, mk4(w.x, w.y), acc2[nt]);
        acc2[nt] = MFMA16(aO, mk4(w.z, w.w), acc2[nt]);
      }
    }
    __builtin_amdgcn_s_setprio(0);
    SBAR();
    // ---- prefetch quarter 4 (raw[12..15]) ----
    if (pf) {
      raw[12] = *(const float4*)(Xn + 192); raw[13] = *(const float4*)(Xn + 196);
      raw[14] = *(const float4*)(Xn + 224); raw[15] = *(const float4*)(Xn + 228);
    }
    SBAR();

    // ---------- mix2: out^T = C2^T * Ahat_ext (+b2 via k=14); store ---------
    // acc2[nt][j] = C2[node=4*lgrp+j][w2col=16*nt+lrow]
    float* outB = out + (size_t)b * 896;
    #pragma unroll
    for (int nt = 0; nt < 4; ++nt) {
      const unsigned a0 = pk2(acc2[nt][0], acc2[nt][1]);
      const unsigned a1 = isg3 ? b2inj[nt] : pk2(acc2[nt][2], acc2[nt][3]);
      const f32x4 o = MFMA16(mk4(a0, a1), amx, zacc);
      // o[j] = out[node=lrow][w2col=16*nt+4*lgrp+j]
      if (lrow < 14) {
        float4 st; st.x = o[0]; st.y = o[1]; st.z = o[2]; st.w = o[3];
        *(float4*)(outB + lrow * 64 + nt * 16 + lgrp * 4) = st;
      }
    }
  }
}

extern "C" void kernel_launch(void* const* d_in, const int* in_sizes, int n_in,
                              void* d_out, int out_size, void* d_ws, size_t ws_size,
                              hipStream_t stream) {
  (void)n_in; (void)out_size; (void)ws_size;
  const float* fea = (const float*)d_in[0];
  const float* W1  = (const float*)d_in[1];
  const float* b1  = (const float*)d_in[2];
  const float* W2  = (const float*)d_in[3];
  const float* b2  = (const float*)d_in[4];
  float* out = (float*)d_out;
  const int Btot = in_sizes[0] / (14 * 256);

  unsigned short* wf = (unsigned short*)d_ws;    // needs 80 KiB of d_ws
  prep_w<<<20, 256, 0, stream>>>(W1, W2, wf);

  const int per_block = 8 * NPW;
  const int grid = (Btot + per_block - 1) / per_block;
  fpm_kernel<<<grid, 512, 0, stream>>>(fea, wf, b1, b2, out, Btot);
}

// Round 13
// 69.035 us; speedup vs baseline: 4.4795x; 1.0000x over previous
//
#include <hip/hip_runtime.h>
#include <hip/hip_bf16.h>

typedef __attribute__((ext_vector_type(8))) short bf16x8;
typedef __attribute__((ext_vector_type(4))) short bf16x4;
typedef __attribute__((ext_vector_type(4))) float f32x4;

#define NPW 4   // batches per wave

#define A3  0.33333334f
#define B4  0.25f
#define C34 0.28867513f

// Per-row sparse A_hat (includes diagonal): up to 4 (neighbor, weight) pairs.
__device__ const int ADJ_IDX[16][4] = {
  {0,1,7,0},{1,0,2,8},{2,1,3,9},{3,2,4,10},
  {4,3,5,11},{5,4,6,12},{6,5,13,0},{7,0,8,0},
  {8,7,9,1},{9,8,10,2},{10,9,11,3},{11,10,12,4},
  {12,11,13,5},{13,12,6,0},{0,0,0,0},{0,0,0,0}
};
__device__ const float ADJ_W[16][4] = {
  {A3,C34,A3,0.f},{B4,C34,B4,B4},{B4,B4,B4,B4},{B4,B4,B4,B4},
  {B4,B4,B4,B4},{B4,B4,C34,B4},{A3,C34,A3,0.f},{A3,A3,C34,0.f},
  {B4,C34,B4,B4},{B4,B4,B4,B4},{B4,B4,B4,B4},{B4,B4,B4,B4},
  {B4,B4,C34,B4},{A3,C34,A3,0.f},{0.f,0.f,0.f,0.f},{0.f,0.f,0.f,0.f}
};

__device__ __forceinline__ unsigned short f2b(float x) {
  unsigned u = __builtin_bit_cast(unsigned, x);
  u += 0x7FFFu + ((u >> 16) & 1u);   // RNE bf16
  return (unsigned short)(u >> 16);
}
// packed f32x2 -> bf16x2 (emits v_cvt_pk_bf16_f32)
__device__ __forceinline__ unsigned pk2(float lo, float hi) {
  float2 t; t.x = lo; t.y = hi;
  __hip_bfloat162 h = __float22bfloat162_rn(t);
  unsigned u; __builtin_memcpy(&u, &h, 4);
  return u;
}
__device__ __forceinline__ bf16x4 mk4(unsigned lo, unsigned hi) {
  uint2 u; u.x = lo; u.y = hi;
  return __builtin_bit_cast(bf16x4, u);
}

#if __has_builtin(__builtin_amdgcn_mfma_f32_16x16x16_bf16)
#define MFMA16(a, b, c) __builtin_amdgcn_mfma_f32_16x16x16_bf16((a), (b), (c), 0, 0, 0)
#elif __has_builtin(__builtin_amdgcn_mfma_f32_16x16x16bf16_1k)
#define MFMA16(a, b, c) __builtin_amdgcn_mfma_f32_16x16x16bf16_1k((a), (b), (c), 0, 0, 0)
#else
__device__ __forceinline__ f32x4 mfma16_asm(bf16x4 a, bf16x4 b, f32x4 c) {
  f32x4 d;
  asm("v_mfma_f32_16x16x16_bf16 %0, %1, %2, %3\n\ts_nop 7\n\ts_nop 7"
      : "=v"(d) : "v"(a), "v"(b), "v"(c));
  return d;
}
#define MFMA16(a, b, c) mfma16_asm((a), (b), (c))
#endif

#define SBAR() __builtin_amdgcn_sched_barrier(0)

// ---------- weight prep ----------
// W1 (K=32 B-frags): frag (nt*8+kk); lane holds W1[kk*32+lgrp*8+j][nt*16+lrow],
//   j=0..8 (16B). At wf ushort-offset [0, 32768).
// W2 (K=16 B-frags, PAIRED): uint4 index (nt*4+kp)*64+lane holds frags
//   kt2=2kp (xy) and kt2=2kp+1 (zw): W2[kt2*16+lgrp*4+i][nt*16+lrow], i=0..4.
//   At wf ushort-offset [32768, 40960).
__global__ __launch_bounds__(256) void prep_w(
    const float* __restrict__ W1, const float* __restrict__ W2,
    unsigned short* __restrict__ wf)
{
  const int f = blockIdx.x * 256 + threadIdx.x;   // 20 blocks -> 5120
  if (f < 4096) {
    const int lane = f & 63, kk = (f >> 6) & 7, nt = f >> 9;
    const int col = nt * 16 + (lane & 15);
    const int k0  = kk * 32 + (lane >> 4) * 8;
    unsigned short tmp[8];
    #pragma unroll
    for (int j = 0; j < 8; ++j) tmp[j] = f2b(W1[(k0 + j) * 128 + col]);
    *(uint4*)(wf + (size_t)f * 8) = *(const uint4*)tmp;
  } else if (f < 5120) {
    const int f2i = f - 4096;                     // 0..1023
    const int lane = f2i & 63, kp = (f2i >> 6) & 3, nt = f2i >> 8;
    const int col = nt * 16 + (lane & 15);
    const int k0  = kp * 32 + (lane >> 4) * 4;    // kt2=2kp -> k = 2kp*16 + lgrp*4
    uint4 q;
    q.x = (unsigned)f2b(W2[(k0 + 0) * 64 + col]) | ((unsigned)f2b(W2[(k0 + 1) * 64 + col]) << 16);
    q.y = (unsigned)f2b(W2[(k0 + 2) * 64 + col]) | ((unsigned)f2b(W2[(k0 + 3) * 64 + col]) << 16);
    q.z = (unsigned)f2b(W2[(k0 + 16) * 64 + col]) | ((unsigned)f2b(W2[(k0 + 17) * 64 + col]) << 16);
    q.w = (unsigned)f2b(W2[(k0 + 18) * 64 + col]) | ((unsigned)f2b(W2[(k0 + 19) * 64 + col]) << 16);
    *(uint4*)(wf + 32768 + (size_t)f2i * 8) = q;
  }
}

__global__ __launch_bounds__(512) void fpm_kernel(
    const float* __restrict__ X,
    const unsigned short* __restrict__ wf,
    const float* __restrict__ b1, const float* __restrict__ b2,
    float* __restrict__ out, int Btot)
{
  __shared__ __align__(16) uint4 WL1[4096];   // 64 KiB W1 frags
  __shared__ __align__(16) uint4 WL2[1024];   // 16 KiB paired W2 frags

  const int tid  = threadIdx.x;
  const int lane = tid & 63;
  const int wv   = tid >> 6;      // 0..7
  const int lrow = lane & 15;
  const int lgrp = lane >> 4;

  const int gw    = blockIdx.x * 8 + wv;
  const int bbase = gw * NPW;

  // ---- issue first batch's X loads ASAP (in flight across LDS fill) ----
  float4 raw[16];
  #pragma unroll
  for (int i = 0; i < 16; ++i) raw[i] = float4{0.f, 0.f, 0.f, 0.f};
  const bool ld_ok = (bbase < Btot) && (lrow < 14);
  if (ld_ok) {
    const float* Xp = X + (size_t)bbase * 3584 + lrow * 256 + lgrp * 8;
    #pragma unroll
    for (int kk = 0; kk < 8; ++kk) {
      raw[2 * kk]     = *(const float4*)(Xp + kk * 32);
      raw[2 * kk + 1] = *(const float4*)(Xp + kk * 32 + 4);
    }
  }

  // ---- one-time LDS fill (read-only afterwards) ----
  #pragma unroll
  for (int i = 0; i < 8; ++i)
    WL1[i * 512 + tid] = ((const uint4*)wf)[i * 512 + tid];
  if (tid < 256) {
    const uint4* wf2 = (const uint4*)(wf + 32768);
    #pragma unroll
    for (int i = 0; i < 4; ++i)
      WL2[i * 256 + tid] = wf2[i * 256 + tid];
  }

  // ---- A_hat K16 B-fragment: B[k=4*lgrp+i][n=lrow]; k=14 row = 1 (bias) ----
  unsigned amx0, amx1;
  {
    float v[4];
    #pragma unroll
    for (int i = 0; i < 4; ++i) {
      const int k = lgrp * 4 + i;
      float s = 0.f;
      if (k == 14) s = 1.f;
      else if (k < 14 && lrow < 14) {
        #pragma unroll
        for (int t = 0; t < 4; ++t)
          if (ADJ_IDX[k][t] == lrow) s += ADJ_W[k][t];
      }
      v[i] = s;
    }
    amx0 = pk2(v[0], v[1]);
    amx1 = pk2(v[2], v[3]);
  }
  const bf16x4 amx = mk4(amx0, amx1);

  unsigned b1inj[8], b2inj[4];
  #pragma unroll
  for (int mt = 0; mt < 8; ++mt) b1inj[mt] = (unsigned)f2b(b1[mt * 16 + lrow]);
  #pragma unroll
  for (int nt = 0; nt < 4; ++nt) b2inj[nt] = (unsigned)f2b(b2[nt * 16 + lrow]);
  const bool isg3 = (lgrp == 3);

  __syncthreads();   // the ONLY block-wide barrier

  const bf16x8* WL1v = (const bf16x8*)WL1;
  const f32x4 zacc = {0.f, 0.f, 0.f, 0.f};

  for (int bi = 0; bi < NPW; ++bi) {
    const int b = bbase + bi;
    if (b >= Btot) break;   // wave-uniform
    const bool pf = (bi + 1 < NPW) && (b + 1 < Btot) && (lrow < 14);
    const float* Xn = X + (size_t)(b + 1) * 3584 + lrow * 256 + lgrp * 8;

    // ---------- upfront cvt: raw -> xfw (raw dies; 32 packed regs) ----------
    unsigned xfw[32];
    #pragma unroll
    for (int i = 0; i < 16; ++i) {
      xfw[2 * i]     = pk2(raw[i].x, raw[i].y);
      xfw[2 * i + 1] = pk2(raw[i].z, raw[i].w);
    }
    SBAR();
    // ---- prefetch quarter 1 (raw[0..3]) ----
    if (pf) {
      raw[0] = *(const float4*)(Xn);       raw[1] = *(const float4*)(Xn + 4);
      raw[2] = *(const float4*)(Xn + 32);  raw[3] = *(const float4*)(Xn + 36);
    }
    SBAR();

    // ---------- GEMM1 + mix1 in TWO nt-chunks of 4 ----------
    // acc1 shrinks to 4 f32x4 (16 AGPR): total regs <= 128 -> 4 waves/SIMD.
    unsigned h1p[8][2];
    #pragma unroll
    for (int half = 0; half < 2; ++half) {
      f32x4 acc1[4];
      #pragma unroll
      for (int q = 0; q < 4; ++q) acc1[q] = zacc;
      __builtin_amdgcn_s_setprio(1);
      #pragma unroll
      for (int kk = 0; kk < 8; ++kk) {
        uint4 t;
        t.x = xfw[4 * kk];     t.y = xfw[4 * kk + 1];
        t.z = xfw[4 * kk + 2]; t.w = xfw[4 * kk + 3];
        const bf16x8 a = __builtin_bit_cast(bf16x8, t);
        #pragma unroll
        for (int q = 0; q < 4; ++q)
          acc1[q] = __builtin_amdgcn_mfma_f32_16x16x32_bf16(
              a, WL1v[((half * 4 + q) * 8 + kk) * 64 + lane], acc1[q], 0, 0, 0);
      }
      __builtin_amdgcn_s_setprio(0);
      // mix1 for this chunk: H1^T = G^T * Ahat_ext (K=16, lane-local A-frags)
      // acc1[q][j] = G[node=4*lgrp+j][col=16*(half*4+q)+lrow]
      #pragma unroll
      for (int q = 0; q < 4; ++q) {
        const int mt = half * 4 + q;
        const unsigned a0 = pk2(acc1[q][0], acc1[q][1]);
        const unsigned a1 = isg3 ? b1inj[mt] : pk2(acc1[q][2], acc1[q][3]);
        const f32x4 h = MFMA16(mk4(a0, a1), amx, zacc);
        // h[j] = H1[node'=lrow][col=16*mt+4*lgrp+j]; relu + pack
        h1p[mt][0] = pk2(fmaxf(h[0], 0.f), fmaxf(h[1], 0.f));
        h1p[mt][1] = pk2(fmaxf(h[2], 0.f), fmaxf(h[3], 0.f));
      }
      SBAR();
      // ---- prefetch quarter 2 (after chunk0) / quarter 3 (after chunk1) ----
      if (pf) {
        if (half == 0) {
          raw[4] = *(const float4*)(Xn + 64);  raw[5] = *(const float4*)(Xn + 68);
          raw[6] = *(const float4*)(Xn + 96);  raw[7] = *(const float4*)(Xn + 100);
        } else {
          raw[8]  = *(const float4*)(Xn + 128); raw[9]  = *(const float4*)(Xn + 132);
          raw[10] = *(const float4*)(Xn + 160); raw[11] = *(const float4*)(Xn + 164);
        }
      }
      SBAR();
    }

    // ---------- GEMM2: C2 = H1 * W2 (M16 x N64 x K128, 8 x K16) -------------
    // A-frag kt2: lane holds H1[lrow][16*kt2+4*lgrp+i]  ==  h1p[kt2] directly.
    f32x4 acc2[4];
    #pragma unroll
    for (int nt = 0; nt < 4; ++nt) acc2[nt] = zacc;
    __builtin_amdgcn_s_setprio(1);
    #pragma unroll
    for (int kp = 0; kp < 4; ++kp) {
      const bf16x4 aE = mk4(h1p[2 * kp][0],     h1p[2 * kp][1]);
      const bf16x4 aO = mk4(h1p[2 * kp + 1][0], h1p[2 * kp + 1][1]);
      #pragma unroll
      for (int nt = 0; nt < 4; ++nt) {
        const uint4 w = WL2[(nt * 4 + kp) * 64 + lane];
        acc2[nt] = MFMA16(aE, mk4(w.x, w.y), acc2[nt]);
        acc2[nt] = MFMA16(aO, mk4(w.z, w.w), acc2[nt]);
      }
    }
    __builtin_amdgcn_s_setprio(0);
    SBAR();
    // ---- prefetch quarter 4 (raw[12..15]) ----
    if (pf) {
      raw[12] = *(const float4*)(Xn + 192); raw[13] = *(const float4*)(Xn + 196);
      raw[14] = *(const float4*)(Xn + 224); raw[15] = *(const float4*)(Xn + 228);
    }
    SBAR();

    // ---------- mix2: out^T = C2^T * Ahat_ext (+b2 via k=14); store ---------
    // acc2[nt][j] = C2[node=4*lgrp+j][w2col=16*nt+lrow]
    float* outB = out + (size_t)b * 896;
    #pragma unroll
    for (int nt = 0; nt < 4; ++nt) {
      const unsigned a0 = pk2(acc2[nt][0], acc2[nt][1]);
      const unsigned a1 = isg3 ? b2inj[nt] : pk2(acc2[nt][2], acc2[nt][3]);
      const f32x4 o = MFMA16(mk4(a0, a1), amx, zacc);
      // o[j] = out[node=lrow][w2col=16*nt+4*lgrp+j]
      if (lrow < 14) {
        float4 st; st.x = o[0]; st.y = o[1]; st.z = o[2]; st.w = o[3];
        *(float4*)(outB + lrow * 64 + nt * 16 + lgrp * 4) = st;
      }
    }
  }
}

extern "C" void kernel_launch(void* const* d_in, const int* in_sizes, int n_in,
                              void* d_out, int out_size, void* d_ws, size_t ws_size,
                              hipStream_t stream) {
  (void)n_in; (void)out_size; (void)ws_size;
  const float* fea = (const float*)d_in[0];
  const float* W1  = (const float*)d_in[1];
  const float* b1  = (const float*)d_in[2];
  const float* W2  = (const float*)d_in[3];
  const float* b2  = (const float*)d_in[4];
  float* out = (float*)d_out;
  const int Btot = in_sizes[0] / (14 * 256);

  unsigned short* wf = (unsigned short*)d_ws;    // needs 80 KiB of d_ws
  prep_w<<<20, 256, 0, stream>>>(W1, W2, wf);

  const int per_block = 8 * NPW;
  const int grid = (Btot + per_block - 1) / per_block;
  fpm_kernel<<<grid, 512, 0, stream>>>(fea, wf, b1, b2, out, Btot);
}